// Round 2
// baseline (728.156 us; speedup 1.0000x reference)
//
#include <hip/hip_runtime.h>

#define NCH 32

// 4x32 FMA block: acc[ch] += g.{x,y,z,w} * w[comp*32 + ch]. W addresses are
// wave-uniform -> compiler emits s_load + v_fmac with SGPR operand.
__device__ __forceinline__ void fma_chunk(float* acc, const float4 g, const float* __restrict__ w)
{
#pragma unroll
    for (int ch = 0; ch < NCH; ++ch) acc[ch] = fmaf(g.x, w[ch], acc[ch]);
#pragma unroll
    for (int ch = 0; ch < NCH; ++ch) acc[ch] = fmaf(g.y, w[NCH + ch], acc[ch]);
#pragma unroll
    for (int ch = 0; ch < NCH; ++ch) acc[ch] = fmaf(g.z, w[2 * NCH + ch], acc[ch]);
#pragma unroll
    for (int ch = 0; ch < NCH; ++ch) acc[ch] = fmaf(g.w, w[3 * NCH + ch], acc[ch]);
}

// Factorized 1D sparse conv, branchless: invalid neighbors are redirected to
// the (always-cached) self row and their contribution zeroed. All 24 float4
// gathers issue before the FMA blocks -> high memory-level parallelism.
// Tap k=1 is the identity (nbr[a][1][p] == p by construction) -> no idx load.
__global__ __launch_bounds__(256) void conv1d_kernel(
    const float* __restrict__ f, const float* __restrict__ W,
    const int* __restrict__ idx, float* __restrict__ out, int n)
{
    int p = blockIdx.x * 256 + threadIdx.x;
    if (p >= n) return;

    int i0 = idx[p];                     // tap -1
    int i2 = idx[(size_t)2 * n + p];     // tap +1
    bool v0 = (i0 < n), v2 = (i2 < n);

    const float4* r1p = (const float4*)(f + (size_t)p * NCH);
    const float4* r0p = (const float4*)(f + (size_t)(v0 ? i0 : p) * NCH);
    const float4* r2p = (const float4*)(f + (size_t)(v2 ? i2 : p) * NCH);

    float4 g1[8], g0[8], g2[8];
#pragma unroll
    for (int c4 = 0; c4 < 8; ++c4) g1[c4] = r1p[c4];
#pragma unroll
    for (int c4 = 0; c4 < 8; ++c4) g0[c4] = r0p[c4];
#pragma unroll
    for (int c4 = 0; c4 < 8; ++c4) g2[c4] = r2p[c4];

    float z0 = v0 ? 1.f : 0.f, z2 = v2 ? 1.f : 0.f;
#pragma unroll
    for (int c4 = 0; c4 < 8; ++c4) {
        g0[c4].x *= z0; g0[c4].y *= z0; g0[c4].z *= z0; g0[c4].w *= z0;
        g2[c4].x *= z2; g2[c4].y *= z2; g2[c4].z *= z2; g2[c4].w *= z2;
    }

    float acc[NCH];
#pragma unroll
    for (int ch = 0; ch < NCH; ++ch) acc[ch] = 0.f;

    // self tap first (its loads were issued first)
#pragma unroll
    for (int c4 = 0; c4 < 8; ++c4) fma_chunk(acc, g1[c4], W + (1 * NCH + c4 * 4) * NCH);
#pragma unroll
    for (int c4 = 0; c4 < 8; ++c4) fma_chunk(acc, g0[c4], W + (0 * NCH + c4 * 4) * NCH);
#pragma unroll
    for (int c4 = 0; c4 < 8; ++c4) fma_chunk(acc, g2[c4], W + (2 * NCH + c4 * 4) * NCH);

    float4* orow = (float4*)(out + (size_t)p * NCH);
#pragma unroll
    for (int c4 = 0; c4 < NCH / 4; ++c4) {
        float4 v;
        v.x = acc[c4 * 4 + 0];
        v.y = acc[c4 * 4 + 1];
        v.z = acc[c4 * 4 + 2];
        v.w = acc[c4 * 4 + 3];
        orow[c4] = v;
    }
}

// Stage 1: per-block partial per-channel sum / sumsq over h [n,32], float4 loads.
// partials[b*64 + c] = sum for channel c (c<32), sumsq for channel c-32 (c>=32).
__global__ __launch_bounds__(256) void stats_partial_kernel(
    const float* __restrict__ h, float* __restrict__ partials, int n)
{
    __shared__ float lsum[4][8][4];
    __shared__ float lsq[4][8][4];

    long total4 = (long)n * 8;
    long tid = (long)blockIdx.x * 256 + threadIdx.x;
    long stride = (long)gridDim.x * 256;   // multiple of 8 -> channel group fixed

    float s[4] = {0.f, 0.f, 0.f, 0.f};
    float q[4] = {0.f, 0.f, 0.f, 0.f};
    for (long i = tid; i < total4; i += stride) {
        float4 v = ((const float4*)h)[i];
        s[0] += v.x; q[0] = fmaf(v.x, v.x, q[0]);
        s[1] += v.y; q[1] = fmaf(v.y, v.y, q[1]);
        s[2] += v.z; q[2] = fmaf(v.z, v.z, q[2]);
        s[3] += v.w; q[3] = fmaf(v.w, v.w, q[3]);
    }

    // reduce lanes sharing the same channel group (lane&7)
#pragma unroll
    for (int off = 8; off < 64; off <<= 1) {
#pragma unroll
        for (int j = 0; j < 4; ++j) {
            s[j] += __shfl_xor(s[j], off);
            q[j] += __shfl_xor(q[j], off);
        }
    }

    int wave = threadIdx.x >> 6;
    int lane = threadIdx.x & 63;
    if (lane < 8) {
#pragma unroll
        for (int j = 0; j < 4; ++j) {
            lsum[wave][lane][j] = s[j];
            lsq[wave][lane][j] = q[j];
        }
    }
    __syncthreads();
    if (threadIdx.x < 64) {
        int t = threadIdx.x;
        float v;
        if (t < 32) {
            v = lsum[0][t >> 2][t & 3] + lsum[1][t >> 2][t & 3]
              + lsum[2][t >> 2][t & 3] + lsum[3][t >> 2][t & 3];
        } else {
            int c = t - 32;
            v = lsq[0][c >> 2][c & 3] + lsq[1][c >> 2][c & 3]
              + lsq[2][c >> 2][c & 3] + lsq[3][c >> 2][c & 3];
        }
        partials[(size_t)blockIdx.x * 64 + t] = v;
    }
}

// Stage 2: one block reduces all partials and emits per-channel scale/shift.
// scaleshift[c] = gamma*rsqrt(var+eps), scaleshift[32+c] = beta - mean*scale.
__global__ __launch_bounds__(256) void stats_finalize_kernel(
    const float* __restrict__ partials, int nparts,
    const float* __restrict__ gamma, const float* __restrict__ beta,
    float* __restrict__ scaleshift, int n)
{
    __shared__ float l[4][64];
    int c = threadIdx.x & 63;
    int r = threadIdx.x >> 6;
    float s = 0.f;
    for (int b = r; b < nparts; b += 4) s += partials[(size_t)b * 64 + c];
    l[r][c] = s;
    __syncthreads();
    if (threadIdx.x < 64) {
        float tot = l[0][c] + l[1][c] + l[2][c] + l[3][c];
        float other = __shfl(tot, c ^ 32);   // pair sum <-> sumsq
        if (c < 32) {
            float inv_n = 1.f / (float)n;
            float mean = tot * inv_n;
            float var = other * inv_n - mean * mean;
            float sc = gamma[c] * rsqrtf(var + 1e-5f);
            float sh = beta[c] - mean * sc;
            scaleshift[c] = sc;
            scaleshift[32 + c] = sh;
        }
    }
}

// BatchNorm + ReLU in place on h [n,32] using precomputed scale/shift.
__global__ __launch_bounds__(256) void bn_relu_kernel(
    float* h, const float* __restrict__ scaleshift, int n)
{
    long tid = (long)blockIdx.x * 256 + threadIdx.x;
    long total4 = (long)n * 8;
    if (tid >= total4) return;

    int ch0 = ((int)(tid & 7)) * 4;
    float4 v = ((const float4*)h)[tid];
    float r[4] = {v.x, v.y, v.z, v.w};
#pragma unroll
    for (int j = 0; j < 4; ++j) {
        int ch = ch0 + j;
        float o = fmaf(r[j], scaleshift[ch], scaleshift[32 + ch]);
        r[j] = o > 0.f ? o : 0.f;
    }
    float4 o4;
    o4.x = r[0]; o4.y = r[1]; o4.z = r[2]; o4.w = r[3];
    ((float4*)h)[tid] = o4;
}

extern "C" void kernel_launch(void* const* d_in, const int* in_sizes, int n_in,
                              void* d_out, int out_size, void* d_ws, size_t ws_size,
                              hipStream_t stream)
{
    const float* feats = (const float*)d_in[0];
    const float* W1    = (const float*)d_in[1];
    const float* W2    = (const float*)d_in[2];
    const float* W3    = (const float*)d_in[3];
    const float* gamma = (const float*)d_in[4];
    const float* beta  = (const float*)d_in[5];
    const int*   nbr   = (const int*)d_in[6];   // [3 axes][3 taps][n]

    int n = in_sizes[0] / NCH;

    float* hout = (float*)d_out;                 // h1, then h3, then final out
    float* h2   = (float*)d_ws;                  // n*32 floats (dead after conv3)

    const int STAT_BLOCKS = 1024;
    float* partials  = (float*)d_ws;             // reuses h2 region (dead)
    float* scaleshift = partials + (size_t)STAT_BLOCKS * 64;

    int cblocks = (n + 255) / 256;

    // conv1: axis 2 (z), feats -> d_out
    conv1d_kernel<<<cblocks, 256, 0, stream>>>(feats, W1, nbr + (size_t)2 * 3 * n, hout, n);
    // conv2: axis 1 (y), d_out -> ws
    conv1d_kernel<<<cblocks, 256, 0, stream>>>(hout, W2, nbr + (size_t)1 * 3 * n, h2, n);
    // conv3: axis 0 (x), ws -> d_out
    conv1d_kernel<<<cblocks, 256, 0, stream>>>(h2, W3, nbr + (size_t)0 * 3 * n, hout, n);

    // BN stats: partials (no atomics), then 1-block finalize -> scale/shift
    stats_partial_kernel<<<STAT_BLOCKS, 256, 0, stream>>>(hout, partials, n);
    stats_finalize_kernel<<<1, 256, 0, stream>>>(partials, STAT_BLOCKS, gamma, beta, scaleshift, n);

    // BN + ReLU in place
    long total4 = (long)n * 8;
    int nblocks = (int)((total4 + 255) / 256);
    bn_relu_kernel<<<nblocks, 256, 0, stream>>>(hout, scaleshift, n);
}